// Round 1
// baseline (661.593 us; speedup 1.0000x reference)
//
#include <hip/hip_runtime.h>

typedef float f32x4 __attribute__((ext_vector_type(4)));
typedef __bf16 bf16x8 __attribute__((ext_vector_type(8)));
typedef __bf16 bf16x4 __attribute__((ext_vector_type(4)));

struct AdjPtrs { const int* p[10]; };

// ---------------------------------------------------------------------------
// Prep: build combined per-degree weights in bf16, pre-swizzled to MFMA
// B-fragment order: wfrag[((d*8+ks)*8+nt)*64 + lane][j] = W_d[k][n],
//   k = ks*32 + (lane>>4)*8 + j,  n = nt*16 + (lane&15)
// W_d rows 0..127 = W_rel[d-1] (0 for d==0), rows 128..255 = W_self[d-1] (W0 for d==0)
// biasall[d*128+c] = b_rel+b_self (b0 for d==0)
// ---------------------------------------------------------------------------
__global__ void gc_prep(const float* __restrict__ W0, const float* __restrict__ b0,
                        const float* __restrict__ Wrel, const float* __restrict__ brel,
                        const float* __restrict__ Wself, const float* __restrict__ bself,
                        __bf16* __restrict__ wfrag, float* __restrict__ biasall)
{
    const int id = blockIdx.x * 256 + threadIdx.x;   // 1408*256 = 360448 exactly
    {
        const int j    = id & 7;
        const int lane = (id >> 3) & 63;
        const int nt   = (id >> 9) & 7;
        const int ks   = (id >> 12) & 7;
        const int d    = id >> 15;                   // 0..10
        const int k = ks * 32 + (lane >> 4) * 8 + j;
        const int n = nt * 16 + (lane & 15);
        float v;
        if (d == 0)      v = (k < 128) ? 0.0f : W0[(k - 128) * 128 + n];
        else if (k < 128) v = Wrel[((d - 1) * 128 + k) * 128 + n];
        else              v = Wself[((d - 1) * 128 + (k - 128)) * 128 + n];
        wfrag[id] = (__bf16)v;
    }
    if (id < 11 * 128) {
        const int dd = id >> 7, c = id & 127;
        biasall[id] = (dd == 0) ? b0[c] : (brel[(dd - 1) * 128 + c] + bself[(dd - 1) * 128 + c]);
    }
}

// ---------------------------------------------------------------------------
// Swizzled LDS addressing: logical (row, byte) -> physical byte offset.
// Row = 128 bf16 = 256B = 16 x 16B chunks; chunk index XORed with (row&7)
// -> conflict-free ds_read_b128 column reads, free ds_write_b64 writes.
// Same formula used on write and read side (both-sides-or-neither rule).
// ---------------------------------------------------------------------------
__device__ __forceinline__ int lds_off(int row, int byteoff) {
    const int chunk = byteoff >> 4;
    return row * 256 + ((chunk ^ (row & 7)) << 4) + (byteoff & 15);
}

// ---------------------------------------------------------------------------
// Rel staging, templated on degree D so the neighbor loop fully unrolls.
// Chunk-interleaved: thread q of a row owns f32x4 chunks g = q + 4i, so the
// 4 lanes of one row form a single contiguous 64B segment per instruction.
// ---------------------------------------------------------------------------
template<int D>
__device__ __forceinline__ void stage_rel(const int* __restrict__ adjd,
                                          const float* __restrict__ atom,
                                          char* __restrict__ XsB,
                                          int tile, int cnt, int t)
{
    const int r = t >> 2;            // 0..63 local row
    const int q = t & 3;
    const int lr = tile * 64 + r;

    float buf[32];
    #pragma unroll
    for (int i = 0; i < 32; i++) buf[i] = 0.0f;

    if (lr < cnt) {
        const int* arow = adjd + (size_t)lr * D;
        int idx[D];
        #pragma unroll
        for (int e = 0; e < D; e++) idx[e] = arow[e];
        #pragma unroll
        for (int e = 0; e < D; e++) {
            const f32x4* src = (const f32x4*)(atom + (size_t)idx[e] * 128) + q;
            #pragma unroll
            for (int i = 0; i < 8; i++) {
                const f32x4 v = src[4 * i];          // chunk q + 4i
                buf[4*i+0] += v[0]; buf[4*i+1] += v[1];
                buf[4*i+2] += v[2]; buf[4*i+3] += v[3];
            }
        }
        if (D > 1) {
            constexpr float sc = 1.0f / (float)D;
            #pragma unroll
            for (int i = 0; i < 32; i++) buf[i] *= sc;
        }
    }

    // 8 x 8B swizzled LDS writes; 8B-chunk index g matches source f32x4 chunk
    #pragma unroll
    for (int i = 0; i < 8; i++) {
        const int g = q + 4 * i;
        bf16x4 pk;
        pk[0] = (__bf16)buf[4*i+0]; pk[1] = (__bf16)buf[4*i+1];
        pk[2] = (__bf16)buf[4*i+2]; pk[3] = (__bf16)buf[4*i+3];
        *(bf16x4*)(XsB + lds_off(r, g * 8)) = pk;
    }
}

// ---------------------------------------------------------------------------
// Main fused kernel: 64-row x 128-col tile per block, 256 threads (4 waves).
// rel (gather-mean) staged bf16 in 16KB swizzled LDS; self loaded directly
// from global into A-fragments (no LDS). K = 128 rel + 128 self, both against
// the pre-swizzled combined weight block.
// ---------------------------------------------------------------------------
__global__ __launch_bounds__(256, 6) void gc_main(
    const float* __restrict__ atom, AdjPtrs adj,
    const __bf16* __restrict__ wfrag, const float* __restrict__ biasall,
    float* __restrict__ out)
{
    __shared__ __bf16 Xs[64 * 128];          // rel only: 16KB, swizzled
    char* XsB = (char*)Xs;

    // ---- block -> (degree, tile) decode; compile-time segment constants ----
    const int bid = blockIdx.x;
    int d, tb, off, cnt;
    if      (bid < 391)  { d = 0;  tb = 0;    off = 0;      cnt = 25000;  }
    else if (bid < 1173) { d = 1;  tb = 391;  off = 25000;  cnt = 50000;  }
    else if (bid < 2736) { d = 2;  tb = 1173; off = 75000;  cnt = 100000; }
    else if (bid < 5080) { d = 3;  tb = 2736; off = 175000; cnt = 150000; }
    else if (bid < 6643) { d = 4;  tb = 5080; off = 325000; cnt = 100000; }
    else if (bid < 7425) { d = 5;  tb = 6643; off = 425000; cnt = 50000;  }
    else if (bid < 7504) { d = 6;  tb = 7425; off = 475000; cnt = 5000;   }
    else if (bid < 7583) { d = 7;  tb = 7504; off = 480000; cnt = 5000;   }
    else if (bid < 7662) { d = 8;  tb = 7583; off = 485000; cnt = 5000;   }
    else if (bid < 7741) { d = 9;  tb = 7662; off = 490000; cnt = 5000;   }
    else                 { d = 10; tb = 7741; off = 495000; cnt = 5000;   }
    const int tile = bid - tb;
    const int t = threadIdx.x;

    if (d > 0) {
        switch (d) {
            case 1:  stage_rel<1> (adj.p[0], atom, XsB, tile, cnt, t); break;
            case 2:  stage_rel<2> (adj.p[1], atom, XsB, tile, cnt, t); break;
            case 3:  stage_rel<3> (adj.p[2], atom, XsB, tile, cnt, t); break;
            case 4:  stage_rel<4> (adj.p[3], atom, XsB, tile, cnt, t); break;
            case 5:  stage_rel<5> (adj.p[4], atom, XsB, tile, cnt, t); break;
            case 6:  stage_rel<6> (adj.p[5], atom, XsB, tile, cnt, t); break;
            case 7:  stage_rel<7> (adj.p[6], atom, XsB, tile, cnt, t); break;
            case 8:  stage_rel<8> (adj.p[7], atom, XsB, tile, cnt, t); break;
            case 9:  stage_rel<9> (adj.p[8], atom, XsB, tile, cnt, t); break;
            case 10: stage_rel<10>(adj.p[9], atom, XsB, tile, cnt, t); break;
        }
        __syncthreads();
    }

    // ---- wave covers 32 rows x 64 cols ----
    const int lane = t & 63, wave = t >> 6;
    const int m16  = lane & 15, quad = lane >> 4;
    const int mbase = (wave & 1) * 32;       // row base within 64-row tile
    const int ntb   = (wave >> 1) * 4;       // first 16-col tile index (of 8)

    f32x4 acc[2][4];
    {
        f32x4 z; z[0] = 0.0f; z[1] = 0.0f; z[2] = 0.0f; z[3] = 0.0f;
        #pragma unroll
        for (int mi = 0; mi < 2; mi++)
            #pragma unroll
            for (int ni = 0; ni < 4; ni++) acc[mi][ni] = z;
    }

    const bf16x8* wbase = (const bf16x8*)wfrag + (size_t)d * 64 * 64 + lane;

    // ---- issue first round of self A-fragment loads early (hide under rel MFMA) ----
    const int lr0 = tile * 64 + mbase + m16;
    const int lr1 = lr0 + 16;
    const float* srow0 = atom + (size_t)(off + (lr0 < cnt ? lr0 : cnt - 1)) * 128;
    const float* srow1 = atom + (size_t)(off + (lr1 < cnt ? lr1 : cnt - 1)) * 128;
    const int kq = quad * 8;

    f32x4 v00 = ((const f32x4*)(srow0 + kq))[0];
    f32x4 v01 = ((const f32x4*)(srow0 + kq))[1];
    f32x4 v10 = ((const f32x4*)(srow1 + kq))[0];
    f32x4 v11 = ((const f32x4*)(srow1 + kq))[1];

    // ---- rel MFMA: ks 0..3 from swizzled LDS ----
    if (d > 0) {
        #pragma unroll
        for (int ks = 0; ks < 4; ks++) {
            const bf16x8 a0 = *(const bf16x8*)(XsB + lds_off(mbase + m16,      ks * 64 + quad * 16));
            const bf16x8 a1 = *(const bf16x8*)(XsB + lds_off(mbase + 16 + m16, ks * 64 + quad * 16));
            #pragma unroll
            for (int ni = 0; ni < 4; ni++) {
                const bf16x8 b = wbase[(size_t)(ks * 8 + ntb + ni) * 64];
                acc[0][ni] = __builtin_amdgcn_mfma_f32_16x16x32_bf16(a0, b, acc[0][ni], 0, 0, 0);
                acc[1][ni] = __builtin_amdgcn_mfma_f32_16x16x32_bf16(a1, b, acc[1][ni], 0, 0, 0);
            }
        }
    }

    // ---- self MFMA: ks 4..7, A-fragments direct from global, pipelined ----
    #pragma unroll
    for (int ksp = 0; ksp < 4; ksp++) {
        bf16x8 a0, a1;
        #pragma unroll
        for (int j = 0; j < 4; j++) {
            a0[j] = (__bf16)v00[j]; a0[4+j] = (__bf16)v01[j];
            a1[j] = (__bf16)v10[j]; a1[4+j] = (__bf16)v11[j];
        }
        if (ksp < 3) {
            const int k0 = (ksp + 1) * 32 + kq;
            v00 = ((const f32x4*)(srow0 + k0))[0];
            v01 = ((const f32x4*)(srow0 + k0))[1];
            v10 = ((const f32x4*)(srow1 + k0))[0];
            v11 = ((const f32x4*)(srow1 + k0))[1];
        }
        #pragma unroll
        for (int ni = 0; ni < 4; ni++) {
            const bf16x8 b = wbase[(size_t)((ksp + 4) * 8 + ntb + ni) * 64];
            acc[0][ni] = __builtin_amdgcn_mfma_f32_16x16x32_bf16(a0, b, acc[0][ni], 0, 0, 0);
            acc[1][ni] = __builtin_amdgcn_mfma_f32_16x16x32_bf16(a1, b, acc[1][ni], 0, 0, 0);
        }
    }

    // ---- epilogue: bias + relu + masked coalesced nontemporal stores ----
    #pragma unroll
    for (int ni = 0; ni < 4; ni++) {
        const int col = (ntb + ni) * 16 + m16;
        const float bv = biasall[d * 128 + col];
        #pragma unroll
        for (int mi = 0; mi < 2; mi++) {
            #pragma unroll
            for (int rg = 0; rg < 4; rg++) {
                const int lrow = tile * 64 + mbase + mi * 16 + quad * 4 + rg;
                if (lrow < cnt) {
                    const float v = fmaxf(acc[mi][ni][rg] + bv, 0.0f);
                    __builtin_nontemporal_store(v, out + (size_t)(off + lrow) * 128 + col);
                }
            }
        }
    }
}

extern "C" void kernel_launch(void* const* d_in, const int* in_sizes, int n_in,
                              void* d_out, int out_size, void* d_ws, size_t ws_size,
                              hipStream_t stream) {
    const float* atom = (const float*)d_in[0];
    // d_in[1] = deg_slice (compile-time constants, unused)
    AdjPtrs adj;
    for (int i = 0; i < 10; i++) adj.p[i] = (const int*)d_in[2 + i];
    const float* W0    = (const float*)d_in[12];
    const float* b0    = (const float*)d_in[13];
    const float* Wrel  = (const float*)d_in[14];
    const float* brel  = (const float*)d_in[15];
    const float* Wself = (const float*)d_in[16];
    const float* bself = (const float*)d_in[17];

    __bf16* wfrag   = (__bf16*)d_ws;                       // 360448 bf16 = 720896 B
    float*  biasall = (float*)((char*)d_ws + 720896);      // 11*128 f32 = 5632 B

    hipLaunchKernelGGL(gc_prep, dim3(1408), dim3(256), 0, stream,
                       W0, b0, Wrel, brel, Wself, bself, wfrag, biasall);
    hipLaunchKernelGGL(gc_main, dim3(7820), dim3(256), 0, stream,
                       atom, adj, wfrag, biasall, (float*)d_out);
}

// Round 4
// 603.930 us; speedup vs baseline: 1.0955x; 1.0955x over previous
//
#include <hip/hip_runtime.h>

typedef float f32x4 __attribute__((ext_vector_type(4)));
typedef __bf16 bf16x8 __attribute__((ext_vector_type(8)));
typedef __bf16 bf16x4 __attribute__((ext_vector_type(4)));

#define N_ATOMS 500000   // sum(DEG_COUNTS) -- round2/3 had 525000: 12.8MB OOB read, crash

struct AdjPtrs { const int* p[10]; };

// ---------------------------------------------------------------------------
// Prep: build combined per-degree weights in bf16, pre-swizzled to MFMA
// B-fragment order: wfrag[((d*8+ks)*8+nt)*64 + lane][j] = W_d[k][n],
//   k = ks*32 + (lane>>4)*8 + j,  n = nt*16 + (lane&15)
// W_d rows 0..127 = W_rel[d-1] (0 for d==0), rows 128..255 = W_self[d-1] (W0 for d==0)
// biasall[d*128+c] = b_rel+b_self (b0 for d==0)
// ---------------------------------------------------------------------------
__global__ void gc_prep(const float* __restrict__ W0, const float* __restrict__ b0,
                        const float* __restrict__ Wrel, const float* __restrict__ brel,
                        const float* __restrict__ Wself, const float* __restrict__ bself,
                        __bf16* __restrict__ wfrag, float* __restrict__ biasall)
{
    const int id = blockIdx.x * 256 + threadIdx.x;   // 1408*256 = 360448 exactly
    {
        const int j    = id & 7;
        const int lane = (id >> 3) & 63;
        const int nt   = (id >> 9) & 7;
        const int ks   = (id >> 12) & 7;
        const int d    = id >> 15;                   // 0..10
        const int k = ks * 32 + (lane >> 4) * 8 + j;
        const int n = nt * 16 + (lane & 15);
        float v;
        if (d == 0)      v = (k < 128) ? 0.0f : W0[(k - 128) * 128 + n];
        else if (k < 128) v = Wrel[((d - 1) * 128 + k) * 128 + n];
        else              v = Wself[((d - 1) * 128 + (k - 128)) * 128 + n];
        wfrag[id] = (__bf16)v;
    }
    if (id < 11 * 128) {
        const int dd = id >> 7, c = id & 127;
        biasall[id] = (dd == 0) ? b0[c] : (brel[(dd - 1) * 128 + c] + bself[(dd - 1) * 128 + c]);
    }
}

// ---------------------------------------------------------------------------
// Conversion pass: atom f32 table (256MB) -> bf16 table (128MB, L3-resident).
// ---------------------------------------------------------------------------
__global__ __launch_bounds__(256) void gc_conv(const float* __restrict__ atom,
                                               __bf16* __restrict__ atomb)
{
    const long total  = (long)N_ATOMS * 16;          // bf16x8 chunks (8.0M)
    const long stride = (long)gridDim.x * 256;
    for (long i = (long)blockIdx.x * 256 + threadIdx.x; i < total; i += stride) {
        const f32x4 a = ((const f32x4*)atom)[2 * i];
        const f32x4 b = ((const f32x4*)atom)[2 * i + 1];
        bf16x8 o;
        o[0] = (__bf16)a[0]; o[1] = (__bf16)a[1]; o[2] = (__bf16)a[2]; o[3] = (__bf16)a[3];
        o[4] = (__bf16)b[0]; o[5] = (__bf16)b[1]; o[6] = (__bf16)b[2]; o[7] = (__bf16)b[3];
        ((bf16x8*)atomb)[i] = o;
    }
}

// ---------------------------------------------------------------------------
// Swizzled LDS addressing: logical (row, byte) -> physical byte offset.
// Row = 128 bf16 = 256B = 16 x 16B chunks; chunk index XORed with (row&7).
// ---------------------------------------------------------------------------
__device__ __forceinline__ int lds_off(int row, int byteoff) {
    const int chunk = byteoff >> 4;
    return row * 256 + ((chunk ^ (row & 7)) << 4) + (byteoff & 15);
}

// ---------------------------------------------------------------------------
// Rel staging, templated on degree D (full unroll) and table dtype.
// Chunk-interleaved: thread q of a row owns 16B chunks g = q + 4i -> the 4
// lanes of one row form a single contiguous 64B segment per instruction.
// ---------------------------------------------------------------------------
template<int D, bool BT>
__device__ __forceinline__ void stage_rel(const int* __restrict__ adjd,
                                          const float* __restrict__ atom,
                                          const __bf16* __restrict__ atomb,
                                          char* __restrict__ XsB,
                                          int tile, int cnt, int t)
{
    const int r = t >> 2;            // 0..63 local row
    const int q = t & 3;
    const int lr = tile * 64 + r;

    if constexpr (BT) {
        bf16x8 outv[4];
        #pragma unroll
        for (int i = 0; i < 4; i++)
            #pragma unroll
            for (int j = 0; j < 8; j++) outv[i][j] = (__bf16)0.0f;

        if (lr < cnt) {
            const int* arow = adjd + (size_t)lr * D;
            int idx[D];
            #pragma unroll
            for (int e = 0; e < D; e++) idx[e] = arow[e];
            if constexpr (D == 1) {
                const bf16x8* src = (const bf16x8*)(atomb + (size_t)idx[0] * 128);
                #pragma unroll
                for (int i = 0; i < 4; i++) outv[i] = src[q + 4 * i];
            } else {
                float buf[32];
                #pragma unroll
                for (int i = 0; i < 32; i++) buf[i] = 0.0f;
                #pragma unroll
                for (int e = 0; e < D; e++) {
                    const bf16x8* src = (const bf16x8*)(atomb + (size_t)idx[e] * 128);
                    #pragma unroll
                    for (int i = 0; i < 4; i++) {
                        const bf16x8 v = src[q + 4 * i];
                        #pragma unroll
                        for (int j = 0; j < 8; j++) buf[8 * i + j] += (float)v[j];
                    }
                }
                constexpr float sc = 1.0f / (float)D;
                #pragma unroll
                for (int i = 0; i < 4; i++)
                    #pragma unroll
                    for (int j = 0; j < 8; j++) outv[i][j] = (__bf16)(buf[8 * i + j] * sc);
            }
        }
        #pragma unroll
        for (int i = 0; i < 4; i++)
            *(bf16x8*)(XsB + lds_off(r, (q + 4 * i) * 16)) = outv[i];
    } else {
        float buf[32];
        #pragma unroll
        for (int i = 0; i < 32; i++) buf[i] = 0.0f;
        if (lr < cnt) {
            const int* arow = adjd + (size_t)lr * D;
            int idx[D];
            #pragma unroll
            for (int e = 0; e < D; e++) idx[e] = arow[e];
            #pragma unroll
            for (int e = 0; e < D; e++) {
                const f32x4* src = (const f32x4*)(atom + (size_t)idx[e] * 128) + q;
                #pragma unroll
                for (int i = 0; i < 8; i++) {
                    const f32x4 v = src[4 * i];
                    buf[4*i+0] += v[0]; buf[4*i+1] += v[1];
                    buf[4*i+2] += v[2]; buf[4*i+3] += v[3];
                }
            }
            if (D > 1) {
                constexpr float sc = 1.0f / (float)D;
                #pragma unroll
                for (int i = 0; i < 32; i++) buf[i] *= sc;
            }
        }
        #pragma unroll
        for (int i = 0; i < 8; i++) {
            const int g = q + 4 * i;   // 8B chunk index
            bf16x4 pk;
            pk[0] = (__bf16)buf[4*i+0]; pk[1] = (__bf16)buf[4*i+1];
            pk[2] = (__bf16)buf[4*i+2]; pk[3] = (__bf16)buf[4*i+3];
            *(bf16x4*)(XsB + lds_off(r, g * 8)) = pk;
        }
    }
}

// ---------------------------------------------------------------------------
// Main fused kernel: 64-row x 128-col tile per block, 256 threads (4 waves).
// rel (gather-mean of bf16 table) staged in 16KB swizzled LDS; self loaded
// directly from the bf16 table as A-fragments. Epilogue stages the output
// tile through LDS and issues full-line nontemporal stores (keeps the 256MB
// output stream out of L3 so the bf16 table stays resident).
// ---------------------------------------------------------------------------
template<bool BT>
__global__ __launch_bounds__(256, 6) void gc_main(
    const float* __restrict__ atom, const __bf16* __restrict__ atomb,
    AdjPtrs adj, const __bf16* __restrict__ wfrag, const float* __restrict__ biasall,
    float* __restrict__ out)
{
    __shared__ __align__(16) char smem[32 * 132 * 4];   // 16896B: Xs(16KB) / Xf union
    char*  XsB = smem;
    float* Xf  = (float*)smem;                          // [32][132] epilogue staging

    // ---- block -> (degree, tile) decode; compile-time segment constants ----
    const int bid = blockIdx.x;
    int d, tb, off, cnt;
    if      (bid < 391)  { d = 0;  tb = 0;    off = 0;      cnt = 25000;  }
    else if (bid < 1173) { d = 1;  tb = 391;  off = 25000;  cnt = 50000;  }
    else if (bid < 2736) { d = 2;  tb = 1173; off = 75000;  cnt = 100000; }
    else if (bid < 5080) { d = 3;  tb = 2736; off = 175000; cnt = 150000; }
    else if (bid < 6643) { d = 4;  tb = 5080; off = 325000; cnt = 100000; }
    else if (bid < 7425) { d = 5;  tb = 6643; off = 425000; cnt = 50000;  }
    else if (bid < 7504) { d = 6;  tb = 7425; off = 475000; cnt = 5000;   }
    else if (bid < 7583) { d = 7;  tb = 7504; off = 480000; cnt = 5000;   }
    else if (bid < 7662) { d = 8;  tb = 7583; off = 485000; cnt = 5000;   }
    else if (bid < 7741) { d = 9;  tb = 7662; off = 490000; cnt = 5000;   }
    else                 { d = 10; tb = 7741; off = 495000; cnt = 5000;   }
    const int tile = bid - tb;
    const int t = threadIdx.x;

    if (d > 0) {
        switch (d) {
            case 1:  stage_rel<1,  BT>(adj.p[0], atom, atomb, XsB, tile, cnt, t); break;
            case 2:  stage_rel<2,  BT>(adj.p[1], atom, atomb, XsB, tile, cnt, t); break;
            case 3:  stage_rel<3,  BT>(adj.p[2], atom, atomb, XsB, tile, cnt, t); break;
            case 4:  stage_rel<4,  BT>(adj.p[3], atom, atomb, XsB, tile, cnt, t); break;
            case 5:  stage_rel<5,  BT>(adj.p[4], atom, atomb, XsB, tile, cnt, t); break;
            case 6:  stage_rel<6,  BT>(adj.p[5], atom, atomb, XsB, tile, cnt, t); break;
            case 7:  stage_rel<7,  BT>(adj.p[6], atom, atomb, XsB, tile, cnt, t); break;
            case 8:  stage_rel<8,  BT>(adj.p[7], atom, atomb, XsB, tile, cnt, t); break;
            case 9:  stage_rel<9,  BT>(adj.p[8], atom, atomb, XsB, tile, cnt, t); break;
            case 10: stage_rel<10, BT>(adj.p[9], atom, atomb, XsB, tile, cnt, t); break;
        }
        __syncthreads();
    }

    // ---- wave covers 32 rows x 64 cols ----
    const int lane = t & 63, wave = t >> 6;
    const int m16  = lane & 15, quad = lane >> 4;
    const int mbase = (wave & 1) * 32;       // row base within 64-row tile
    const int ntb   = (wave >> 1) * 4;       // first 16-col tile index (of 8)

    f32x4 acc[2][4];
    {
        f32x4 z; z[0] = 0.0f; z[1] = 0.0f; z[2] = 0.0f; z[3] = 0.0f;
        #pragma unroll
        for (int mi = 0; mi < 2; mi++)
            #pragma unroll
            for (int ni = 0; ni < 4; ni++) acc[mi][ni] = z;
    }

    const bf16x8* wbase = (const bf16x8*)wfrag + (size_t)d * 64 * 64 + lane;

    // ---- self A-fragment sources; first round issued before rel MFMA ----
    const int lr0 = tile * 64 + mbase + m16;
    const int lr1 = lr0 + 16;
    const int cl0 = lr0 < cnt ? lr0 : cnt - 1;
    const int cl1 = lr1 < cnt ? lr1 : cnt - 1;
    const int kq  = quad * 8;

    const __bf16* srow0b = atomb + (size_t)(off + cl0) * 128;
    const __bf16* srow1b = atomb + (size_t)(off + cl1) * 128;
    const float*  srow0f = atom  + (size_t)(off + cl0) * 128;
    const float*  srow1f = atom  + (size_t)(off + cl1) * 128;

    bf16x8 sa0, sa1;
    f32x4 v00, v01, v10, v11;
    if constexpr (BT) {
        sa0 = *(const bf16x8*)(srow0b + kq);
        sa1 = *(const bf16x8*)(srow1b + kq);
    } else {
        v00 = ((const f32x4*)(srow0f + kq))[0];
        v01 = ((const f32x4*)(srow0f + kq))[1];
        v10 = ((const f32x4*)(srow1f + kq))[0];
        v11 = ((const f32x4*)(srow1f + kq))[1];
    }

    // ---- rel MFMA: ks 0..3 from swizzled LDS ----
    if (d > 0) {
        #pragma unroll
        for (int ks = 0; ks < 4; ks++) {
            const bf16x8 a0 = *(const bf16x8*)(XsB + lds_off(mbase + m16,      ks * 64 + quad * 16));
            const bf16x8 a1 = *(const bf16x8*)(XsB + lds_off(mbase + 16 + m16, ks * 64 + quad * 16));
            #pragma unroll
            for (int ni = 0; ni < 4; ni++) {
                const bf16x8 b = wbase[(size_t)(ks * 8 + ntb + ni) * 64];
                acc[0][ni] = __builtin_amdgcn_mfma_f32_16x16x32_bf16(a0, b, acc[0][ni], 0, 0, 0);
                acc[1][ni] = __builtin_amdgcn_mfma_f32_16x16x32_bf16(a1, b, acc[1][ni], 0, 0, 0);
            }
        }
    }

    // ---- self MFMA: ks 4..7, A-fragments direct from table, pipelined ----
    #pragma unroll
    for (int ksp = 0; ksp < 4; ksp++) {
        bf16x8 a0, a1;
        if constexpr (BT) {
            a0 = sa0; a1 = sa1;
            if (ksp < 3) {
                sa0 = *(const bf16x8*)(srow0b + (ksp + 1) * 32 + kq);
                sa1 = *(const bf16x8*)(srow1b + (ksp + 1) * 32 + kq);
            }
        } else {
            #pragma unroll
            for (int j = 0; j < 4; j++) {
                a0[j] = (__bf16)v00[j]; a0[4+j] = (__bf16)v01[j];
                a1[j] = (__bf16)v10[j]; a1[4+j] = (__bf16)v11[j];
            }
            if (ksp < 3) {
                const int k0 = (ksp + 1) * 32 + kq;
                v00 = ((const f32x4*)(srow0f + k0))[0];
                v01 = ((const f32x4*)(srow0f + k0))[1];
                v10 = ((const f32x4*)(srow1f + k0))[0];
                v11 = ((const f32x4*)(srow1f + k0))[1];
            }
        }
        #pragma unroll
        for (int ni = 0; ni < 4; ni++) {
            const bf16x8 b = wbase[(size_t)((ksp + 4) * 8 + ntb + ni) * 64];
            acc[0][ni] = __builtin_amdgcn_mfma_f32_16x16x32_bf16(a0, b, acc[0][ni], 0, 0, 0);
            acc[1][ni] = __builtin_amdgcn_mfma_f32_16x16x32_bf16(a1, b, acc[1][ni], 0, 0, 0);
        }
    }

    // ---- epilogue: bias+relu in regs, stage 32x128 halves in LDS, then
    //      full-line (f32x4 per lane, 1KB per wave-instr) nontemporal stores --
    #pragma unroll
    for (int ni = 0; ni < 4; ni++) {
        const int col = (ntb + ni) * 16 + m16;
        const float bv = biasall[d * 128 + col];
        #pragma unroll
        for (int mi = 0; mi < 2; mi++)
            #pragma unroll
            for (int rg = 0; rg < 4; rg++)
                acc[mi][ni][rg] = fmaxf(acc[mi][ni][rg] + bv, 0.0f);
    }

    #pragma unroll
    for (int pass = 0; pass < 2; pass++) {
        __syncthreads();                       // pass0: all waves done reading Xs
        if ((wave & 1) == pass) {
            #pragma unroll
            for (int ni = 0; ni < 4; ni++) {
                const int col = (ntb + ni) * 16 + m16;
                #pragma unroll
                for (int mi = 0; mi < 2; mi++)
                    #pragma unroll
                    for (int rg = 0; rg < 4; rg++)
                        Xf[(mi * 16 + quad * 4 + rg) * 132 + col] = acc[mi][ni][rg];
            }
        }
        __syncthreads();
        #pragma unroll
        for (int i = 0; i < 4; i++) {
            const int flat = (i * 256 + t) * 4;          // float idx in 32x128 block
            const int r = flat >> 7, c = flat & 127;
            const int lrow = tile * 64 + pass * 32 + r;
            if (lrow < cnt) {
                const f32x4 v = *(const f32x4*)(Xf + r * 132 + c);
                __builtin_nontemporal_store(v, (f32x4*)(out + (size_t)(off + lrow) * 128 + c));
            }
        }
    }
}

extern "C" void kernel_launch(void* const* d_in, const int* in_sizes, int n_in,
                              void* d_out, int out_size, void* d_ws, size_t ws_size,
                              hipStream_t stream) {
    const float* atom = (const float*)d_in[0];
    // d_in[1] = deg_slice (compile-time constants, unused)
    AdjPtrs adj;
    for (int i = 0; i < 10; i++) adj.p[i] = (const int*)d_in[2 + i];
    const float* W0    = (const float*)d_in[12];
    const float* b0    = (const float*)d_in[13];
    const float* Wrel  = (const float*)d_in[14];
    const float* brel  = (const float*)d_in[15];
    const float* Wself = (const float*)d_in[16];
    const float* bself = (const float*)d_in[17];

    __bf16* wfrag   = (__bf16*)d_ws;                       // 360448 bf16 = 720896 B
    float*  biasall = (float*)((char*)d_ws + 720896);      // 11*128 f32 = 5632 B
    __bf16* atomb   = (__bf16*)((char*)d_ws + 726528);     // 500000*128 bf16 = 128 MB

    const size_t need = 726528 + (size_t)N_ATOMS * 128 * 2;

    hipLaunchKernelGGL(gc_prep, dim3(1408), dim3(256), 0, stream,
                       W0, b0, Wrel, brel, Wself, bself, wfrag, biasall);

    if (ws_size >= need) {
        hipLaunchKernelGGL(gc_conv, dim3(2048), dim3(256), 0, stream, atom, atomb);
        hipLaunchKernelGGL(gc_main<true>, dim3(7820), dim3(256), 0, stream,
                           atom, atomb, adj, wfrag, biasall, (float*)d_out);
    } else {
        hipLaunchKernelGGL(gc_main<false>, dim3(7820), dim3(256), 0, stream,
                           atom, atomb, adj, wfrag, biasall, (float*)d_out);
    }
}